// Round 1
// baseline (1826.361 us; speedup 1.0000x reference)
//
#include <hip/hip_runtime.h>

#define D 64
#define NPB 64      // nodes per block in layer kernel
#define RS 68       // padded LDS row stride (floats): conflict-free + 16B-alignable
#define EPSV 1e-5f
#define SLOPE 0.01f

__device__ __forceinline__ float lrelu(float v) { return v > 0.f ? v : SLOPE * v; }

// ---------------- CSR build ----------------

__global__ void count_kernel(const int* __restrict__ dst, int E, int* __restrict__ cnt) {
    int i = blockIdx.x * 256 + threadIdx.x;
    if (i < E) atomicAdd(&cnt[dst[i]], 1);
}

__global__ void scan1_kernel(const int* __restrict__ cnt, int N, int* __restrict__ psum) {
    __shared__ int sd[256];
    int t = threadIdx.x;
    int i = blockIdx.x * 256 + t;
    sd[t] = (i < N) ? cnt[i] : 0;
    __syncthreads();
    for (int o = 128; o > 0; o >>= 1) {
        if (t < o) sd[t] += sd[t + o];
        __syncthreads();
    }
    if (t == 0) psum[blockIdx.x] = sd[0];
}

__global__ void scan2_kernel(int* __restrict__ psum, int nb) {
    __shared__ int sd[1024];
    int t = threadIdx.x;
    int v = (t < nb) ? psum[t] : 0;
    int x = v;
    sd[t] = x;
    __syncthreads();
    for (int o = 1; o < 1024; o <<= 1) {
        int y = (t >= o) ? sd[t - o] : 0;
        __syncthreads();
        x += y;
        sd[t] = x;
        __syncthreads();
    }
    if (t < nb) psum[t] = x - v;  // exclusive
}

__global__ void scan3_kernel(const int* __restrict__ cnt, const int* __restrict__ psum,
                             int N, int E, int* __restrict__ offsets) {
    __shared__ int sd[256];
    int t = threadIdx.x;
    int i = blockIdx.x * 256 + t;
    int v = (i < N) ? cnt[i] : 0;
    int x = v;
    sd[t] = x;
    __syncthreads();
    for (int o = 1; o < 256; o <<= 1) {
        int y = (t >= o) ? sd[t - o] : 0;
        __syncthreads();
        x += y;
        sd[t] = x;
        __syncthreads();
    }
    if (i < N) offsets[i] = psum[blockIdx.x] + x - v;  // exclusive global
    if (i == 0) offsets[N] = E;
}

__global__ void fill_kernel(const int* __restrict__ src, const int* __restrict__ dst, int E,
                            const int* __restrict__ offsets, int* __restrict__ cursor,
                            int* __restrict__ col) {
    int i = blockIdx.x * 256 + threadIdx.x;
    if (i < E) {
        int d = dst[i];
        int p = atomicAdd(&cursor[d], 1);
        col[offsets[d] + p] = src[i];
    }
}

// ---------------- BN stats -> affine (a,c) ----------------

__global__ void affine_kernel(const float* __restrict__ sums, const float* __restrict__ sumsq,
                              const float* __restrict__ g, const float* __restrict__ b,
                              float* __restrict__ a, float* __restrict__ c, float invN) {
    int j = threadIdx.x;  // 64 threads
    float mu  = sums[j] * invN;
    float var = sumsq[j] * invN - mu * mu;
    float aj  = g[j] * rsqrtf(var + EPSV);
    a[j] = aj;
    c[j] = b[j] - mu * aj;
}

// ---------------- fused SAGE layer ----------------
// MODE 0: input raw x, no input affine; outputs h_pre + BN stats
// MODE 1: input h_pre with affine (a,c) folded in; outputs h_pre + BN stats
// MODE 2: input h_pre with affine; fused FC head -> out[N]

template <int MODE>
__global__ __launch_bounds__(256, 2)
void layer_kernel(const float* __restrict__ in,
                  const float* __restrict__ aff_a,
                  const float* __restrict__ aff_c,
                  const int* __restrict__ offsets,
                  const int* __restrict__ col,
                  const float* __restrict__ Wl,
                  const float* __restrict__ bl,
                  const float* __restrict__ Wr,
                  float* __restrict__ hout,
                  float* __restrict__ sums,
                  float* __restrict__ sumsq,
                  const float* __restrict__ wfc,
                  const float* __restrict__ bfc,
                  float* __restrict__ out,
                  int N)
{
    __shared__ float WlS[D * D];
    __shared__ float WrS[D * D];
    __shared__ float aggs[NPB * RS];
    __shared__ float xs[NPB * RS];

    const int tid  = threadIdx.x;
    const int base = blockIdx.x * NPB;
    const int wave = tid >> 6;
    const int lane = tid & 63;

    // stage weights (4096 floats each; 256 threads x 4 float4)
    {
        const float4* wl4 = (const float4*)Wl;
        const float4* wr4 = (const float4*)Wr;
        float4* wls4 = (float4*)WlS;
        float4* wrs4 = (float4*)WrS;
        #pragma unroll
        for (int i = 0; i < 4; ++i) {
            wls4[tid + i * 256] = wl4[tid + i * 256];
            wrs4[tid + i * 256] = wr4[tid + i * 256];
        }
    }
    // stage self rows (+input affine)
    {
        const int r0 = tid >> 4;          // 0..15
        const int c4 = (tid & 15) * 4;    // 0..60
        #pragma unroll
        for (int pp = 0; pp < 4; ++pp) {
            int row = pp * 16 + r0;
            int gn  = base + row;
            float4 v = make_float4(0.f, 0.f, 0.f, 0.f);
            if (gn < N) v = *(const float4*)&in[(size_t)gn * D + c4];
            if (MODE != 0) {
                v.x = v.x * aff_a[c4 + 0] + aff_c[c4 + 0];
                v.y = v.y * aff_a[c4 + 1] + aff_c[c4 + 1];
                v.z = v.z * aff_a[c4 + 2] + aff_c[c4 + 2];
                v.w = v.w * aff_a[c4 + 3] + aff_c[c4 + 3];
            }
            *(float4*)&xs[row * RS + c4] = v;
        }
    }

    // gather-mean: wave w handles nodes w*16..w*16+15; lane = feature
    float av_a = 1.f, av_c = 0.f;
    if (MODE != 0) { av_a = aff_a[lane]; av_c = aff_c[lane]; }
    for (int i = 0; i < 16; ++i) {
        int n  = wave * 16 + i;
        int gn = base + n;
        float acc = 0.f;
        int deg = 0;
        if (gn < N) {
            int beg = offsets[gn];
            int end = offsets[gn + 1];
            deg = end - beg;
            int j = beg;
            for (; j + 4 <= end; j += 4) {
                int c0 = col[j + 0], c1 = col[j + 1], c2 = col[j + 2], c3 = col[j + 3];
                float r0f = in[(size_t)c0 * D + lane];
                float r1f = in[(size_t)c1 * D + lane];
                float r2f = in[(size_t)c2 * D + lane];
                float r3f = in[(size_t)c3 * D + lane];
                acc += (r0f + r1f) + (r2f + r3f);
            }
            for (; j < end; ++j)
                acc += in[(size_t)col[j] * D + lane];
        }
        float agg = 0.f;
        if (deg > 0) {
            agg = acc / (float)deg;
            if (MODE != 0) agg = agg * av_a + av_c;   // deg==0 stays exactly 0 (matches ref)
        }
        aggs[n * RS + lane] = agg;
    }
    __syncthreads();

    // matmul: wave w computes features [w*16, w*16+16) for all 64 nodes; lane = node
    float acc[16];
    #pragma unroll
    for (int jj = 0; jj < 16; ++jj) acc[jj] = 0.f;
    const int jg = wave * 16;
    const int n  = lane;
    for (int k = 0; k < D; k += 4) {
        float4 a4 = *(const float4*)&aggs[n * RS + k];
        float4 x4 = *(const float4*)&xs[n * RS + k];
        const float* ap = (const float*)&a4;
        const float* xp = (const float*)&x4;
        #pragma unroll
        for (int kk = 0; kk < 4; ++kk) {
            const float avv = ap[kk];
            const float xvv = xp[kk];
            const float* wlr = &WlS[(k + kk) * D + jg];
            const float* wrr = &WrS[(k + kk) * D + jg];
            #pragma unroll
            for (int jj = 0; jj < 16; ++jj) {
                acc[jj] += avv * wlr[jj];
                acc[jj] += xvv * wrr[jj];
            }
        }
    }
    __syncthreads();  // all waves done reading aggs/xs

    if (MODE != 2) {
        float hv[16];
        #pragma unroll
        for (int jj = 0; jj < 16; ++jj) {
            float v = acc[jj] + bl[jg + jj];
            hv[jj] = lrelu(v);
        }
        // transpose through LDS (reuse aggs) for coalesced writeback
        #pragma unroll
        for (int q = 0; q < 4; ++q) {
            float4 v4 = make_float4(hv[q * 4 + 0], hv[q * 4 + 1], hv[q * 4 + 2], hv[q * 4 + 3]);
            *(float4*)&aggs[n * RS + jg + q * 4] = v4;
        }
        __syncthreads();
        {
            const int r0 = tid >> 4;
            const int c4 = (tid & 15) * 4;
            #pragma unroll
            for (int pp = 0; pp < 4; ++pp) {
                int row = pp * 16 + r0;
                int gn  = base + row;
                if (gn < N)
                    *(float4*)&hout[(size_t)gn * D + c4] = *(const float4*)&aggs[row * RS + c4];
            }
        }
        // BN partial stats: sum over nodes (= lanes) per feature
        bool valid = (base + n) < N;
        #pragma unroll
        for (int jj = 0; jj < 16; ++jj) {
            float s1 = valid ? hv[jj] : 0.f;
            float s2 = s1 * s1;
            #pragma unroll
            for (int o = 32; o > 0; o >>= 1) {
                s1 += __shfl_xor(s1, o, 64);
                s2 += __shfl_xor(s2, o, 64);
            }
            if (lane == 0) {
                atomicAdd(&sums[jg + jj], s1);
                atomicAdd(&sumsq[jg + jj], s2);
            }
        }
    } else {
        // fused FC head: out[n] = lrelu(h2) . wfc + bfc
        float s = 0.f;
        #pragma unroll
        for (int jj = 0; jj < 16; ++jj) {
            float v = acc[jj] + bl[jg + jj];
            s += lrelu(v) * wfc[jg + jj];
        }
        aggs[wave * 64 + n] = s;   // scratch reuse, post-barrier
        __syncthreads();
        if (wave == 0) {
            int gn = base + lane;
            if (gn < N)
                out[gn] = aggs[lane] + aggs[64 + lane] + aggs[128 + lane] + aggs[192 + lane] + bfc[0];
        }
    }
}

// ---------------- launch ----------------

extern "C" void kernel_launch(void* const* d_in, const int* in_sizes, int n_in,
                              void* d_out, int out_size, void* d_ws, size_t ws_size,
                              hipStream_t stream) {
    const float* x   = (const float*)d_in[0];
    const int*   ei  = (const int*)d_in[1];
    const float* W0l = (const float*)d_in[2];
    const float* b0  = (const float*)d_in[3];
    const float* W0r = (const float*)d_in[4];
    const float* g0  = (const float*)d_in[5];
    const float* be0 = (const float*)d_in[6];
    const float* W1l = (const float*)d_in[7];
    const float* b1  = (const float*)d_in[8];
    const float* W1r = (const float*)d_in[9];
    const float* g1  = (const float*)d_in[10];
    const float* be1 = (const float*)d_in[11];
    const float* W2l = (const float*)d_in[12];
    const float* b2  = (const float*)d_in[13];
    const float* W2r = (const float*)d_in[14];
    const float* Wfc = (const float*)d_in[15];
    const float* bfc = (const float*)d_in[16];
    float* out = (float*)d_out;

    const int N = in_sizes[0] / D;
    const int E = in_sizes[1] / 2;
    const int* src = ei;
    const int* dst = ei + E;

    char* p = (char*)d_ws;
    auto carve = [&](size_t bytes) {
        char* r = p;
        p += (bytes + 255) & ~(size_t)255;
        return r;
    };
    int*   cnt     = (int*)carve((size_t)2 * N * 4);     // cnt + cursor contiguous
    int*   cursor  = cnt + N;
    int*   offsets = (int*)carve((size_t)(N + 1) * 4);
    int*   psum    = (int*)carve(1024 * 4);
    int*   col     = (int*)carve((size_t)E * 4);
    float* stats   = (float*)carve(256 * 4);             // sums0,sumsq0,sums1,sumsq1
    float* aff     = (float*)carve(256 * 4);             // a0,c0,a1,c1
    float* h0      = (float*)carve((size_t)N * D * 4);
    float* h1      = (float*)carve((size_t)N * D * 4);

    hipMemsetAsync(cnt, 0, (size_t)2 * N * 4, stream);
    hipMemsetAsync(stats, 0, 256 * 4, stream);

    const int ebl = (E + 255) / 256;
    const int nbl = (N + 255) / 256;

    count_kernel<<<ebl, 256, 0, stream>>>(dst, E, cnt);
    scan1_kernel<<<nbl, 256, 0, stream>>>(cnt, N, psum);
    scan2_kernel<<<1, 1024, 0, stream>>>(psum, nbl);
    scan3_kernel<<<nbl, 256, 0, stream>>>(cnt, psum, N, E, offsets);
    fill_kernel<<<ebl, 256, 0, stream>>>(src, dst, E, offsets, cursor, col);

    const int lbl = (N + NPB - 1) / NPB;
    const float invN = 1.f / (float)N;

    layer_kernel<0><<<lbl, 256, 0, stream>>>(x, nullptr, nullptr, offsets, col,
                                             W0l, b0, W0r, h0, stats + 0, stats + 64,
                                             nullptr, nullptr, nullptr, N);
    affine_kernel<<<1, 64, 0, stream>>>(stats + 0, stats + 64, g0, be0, aff + 0, aff + 64, invN);
    layer_kernel<1><<<lbl, 256, 0, stream>>>(h0, aff + 0, aff + 64, offsets, col,
                                             W1l, b1, W1r, h1, stats + 128, stats + 192,
                                             nullptr, nullptr, nullptr, N);
    affine_kernel<<<1, 64, 0, stream>>>(stats + 128, stats + 192, g1, be1, aff + 128, aff + 192, invN);
    layer_kernel<2><<<lbl, 256, 0, stream>>>(h1, aff + 128, aff + 192, offsets, col,
                                             W2l, b2, W2r, nullptr, nullptr, nullptr,
                                             Wfc, bfc, out, N);
}

// Round 4
// 1659.151 us; speedup vs baseline: 1.1008x; 1.1008x over previous
//
#include <hip/hip_runtime.h>

#define D 64
#define NPB 64      // nodes per block in layer kernel
#define RS 68       // padded LDS row stride (floats)
#define EPSV 1e-5f
#define SLOPE 0.01f

__device__ __forceinline__ float lrelu(float v) { return v > 0.f ? v : SLOPE * v; }

// ---------------- CSR build ----------------

__global__ void count_kernel(const int* __restrict__ dst, int E, int* __restrict__ cnt) {
    int i = blockIdx.x * 256 + threadIdx.x;
    if (i < E) atomicAdd(&cnt[dst[i]], 1);
}

__global__ void scan1_kernel(const int* __restrict__ cnt, int N, int* __restrict__ psum) {
    __shared__ int sd[256];
    int t = threadIdx.x;
    int i = blockIdx.x * 256 + t;
    sd[t] = (i < N) ? cnt[i] : 0;
    __syncthreads();
    for (int o = 128; o > 0; o >>= 1) {
        if (t < o) sd[t] += sd[t + o];
        __syncthreads();
    }
    if (t == 0) psum[blockIdx.x] = sd[0];
}

__global__ void scan2_kernel(int* __restrict__ psum, int nb) {
    __shared__ int sd[1024];
    int t = threadIdx.x;
    int v = (t < nb) ? psum[t] : 0;
    int x = v;
    sd[t] = x;
    __syncthreads();
    for (int o = 1; o < 1024; o <<= 1) {
        int y = (t >= o) ? sd[t - o] : 0;
        __syncthreads();
        x += y;
        sd[t] = x;
        __syncthreads();
    }
    if (t < nb) psum[t] = x - v;  // exclusive
}

__global__ void scan3_kernel(const int* __restrict__ cnt, const int* __restrict__ psum,
                             int N, int E, int* __restrict__ offsets) {
    __shared__ int sd[256];
    int t = threadIdx.x;
    int i = blockIdx.x * 256 + t;
    int v = (i < N) ? cnt[i] : 0;
    int x = v;
    sd[t] = x;
    __syncthreads();
    for (int o = 1; o < 256; o <<= 1) {
        int y = (t >= o) ? sd[t - o] : 0;
        __syncthreads();
        x += y;
        sd[t] = x;
        __syncthreads();
    }
    if (i < N) offsets[i] = psum[blockIdx.x] + x - v;  // exclusive global
    if (i == 0) offsets[N] = E;
}

__global__ void fill_kernel(const int* __restrict__ src, const int* __restrict__ dst, int E,
                            const int* __restrict__ offsets, int* __restrict__ cursor,
                            int* __restrict__ col) {
    int i = blockIdx.x * 256 + threadIdx.x;
    if (i < E) {
        int d = dst[i];
        int p = atomicAdd(&cursor[d], 1);
        col[offsets[d] + p] = src[i];
    }
}

// ---------------- BN stats -> affine (a,c) ----------------

__global__ void affine_kernel(const float* __restrict__ sums, const float* __restrict__ sumsq,
                              const float* __restrict__ g, const float* __restrict__ b,
                              float* __restrict__ a, float* __restrict__ c, float invN) {
    int j = threadIdx.x;  // 64 threads
    float mu  = sums[j] * invN;
    float var = sumsq[j] * invN - mu * mu;
    float aj  = g[j] * rsqrtf(var + EPSV);
    a[j] = aj;
    c[j] = b[j] - mu * aj;
}

// ---------------- gather-mean kernel: one wave per node ----------------
// AFF=0: agg = mean(in[neighbors])            (deg==0 -> 0)
// AFF=1: agg = affine(mean(in[neighbors]))    (deg==0 -> exact 0, matches ref)

template <int AFF>
__global__ __launch_bounds__(256, 8)
void agg_kernel(const float* __restrict__ in,
                const int* __restrict__ offsets,
                const int* __restrict__ col,
                const float* __restrict__ aff_a,
                const float* __restrict__ aff_c,
                float* __restrict__ aggout,
                int N)
{
    const int node = blockIdx.x * 4 + (threadIdx.x >> 6);
    const int lane = threadIdx.x & 63;
    if (node >= N) return;

    const int beg = offsets[node];
    const int end = offsets[node + 1];
    const int deg = end - beg;

    float a0 = 0.f, a1 = 0.f, a2 = 0.f, a3 = 0.f;
    float a4 = 0.f, a5 = 0.f, a6 = 0.f, a7 = 0.f;

    for (int cb = beg; cb < end; cb += 64) {
        const int nn = min(64, end - cb);
        const int cidx = (lane < nn) ? col[cb + lane] : 0;
        int j = 0;
        for (; j + 8 <= nn; j += 8) {
            const int c0 = __shfl(cidx, j + 0);
            const int c1 = __shfl(cidx, j + 1);
            const int c2 = __shfl(cidx, j + 2);
            const int c3 = __shfl(cidx, j + 3);
            const int c4 = __shfl(cidx, j + 4);
            const int c5 = __shfl(cidx, j + 5);
            const int c6 = __shfl(cidx, j + 6);
            const int c7 = __shfl(cidx, j + 7);
            a0 += in[(size_t)c0 * D + lane];
            a1 += in[(size_t)c1 * D + lane];
            a2 += in[(size_t)c2 * D + lane];
            a3 += in[(size_t)c3 * D + lane];
            a4 += in[(size_t)c4 * D + lane];
            a5 += in[(size_t)c5 * D + lane];
            a6 += in[(size_t)c6 * D + lane];
            a7 += in[(size_t)c7 * D + lane];
        }
        for (; j + 4 <= nn; j += 4) {
            const int c0 = __shfl(cidx, j + 0);
            const int c1 = __shfl(cidx, j + 1);
            const int c2 = __shfl(cidx, j + 2);
            const int c3 = __shfl(cidx, j + 3);
            a0 += in[(size_t)c0 * D + lane];
            a1 += in[(size_t)c1 * D + lane];
            a2 += in[(size_t)c2 * D + lane];
            a3 += in[(size_t)c3 * D + lane];
        }
        for (; j < nn; ++j) {
            const int c = __shfl(cidx, j);
            a0 += in[(size_t)c * D + lane];
        }
    }

    float agg = 0.f;
    if (deg > 0) {
        agg = (((a0 + a1) + (a2 + a3)) + ((a4 + a5) + (a6 + a7))) / (float)deg;
        if (AFF) agg = agg * aff_a[lane] + aff_c[lane];
    }
    aggout[(size_t)node * D + lane] = agg;
}

// ---------------- fused dense layer ----------------
// MODE 0: input raw x (no input affine on self term); outputs h_pre + BN stats
// MODE 1: input h_pre, affine (a,c) folded into self term; outputs h_pre + BN stats
// MODE 2: input h_pre, affine on self term; fused FC head -> out[N]
// agg input rows already have affine applied (by agg_kernel).

template <int MODE>
__global__ __launch_bounds__(256, 2)
void layer_kernel(const float* __restrict__ in,
                  const float* __restrict__ agg,
                  const float* __restrict__ aff_a,
                  const float* __restrict__ aff_c,
                  const float* __restrict__ Wl,
                  const float* __restrict__ bl,
                  const float* __restrict__ Wr,
                  float* __restrict__ hout,
                  float* __restrict__ sums,
                  float* __restrict__ sumsq,
                  const float* __restrict__ wfc,
                  const float* __restrict__ bfc,
                  float* __restrict__ out,
                  int N)
{
    __shared__ float WlS[D * D];
    __shared__ float WrS[D * D];
    __shared__ float aggs[NPB * RS];
    __shared__ float xs[NPB * RS];

    const int tid  = threadIdx.x;
    const int base = blockIdx.x * NPB;
    const int wave = tid >> 6;
    const int lane = tid & 63;

    // stage weights (4096 floats each; 256 threads x 4 float4)
    {
        const float4* wl4 = (const float4*)Wl;
        const float4* wr4 = (const float4*)Wr;
        float4* wls4 = (float4*)WlS;
        float4* wrs4 = (float4*)WrS;
        #pragma unroll
        for (int i = 0; i < 4; ++i) {
            wls4[tid + i * 256] = wl4[tid + i * 256];
            wrs4[tid + i * 256] = wr4[tid + i * 256];
        }
    }
    // stage agg rows + self rows (+input affine on self)
    {
        const int r0 = tid >> 4;          // 0..15
        const int c4 = (tid & 15) * 4;    // 0..60
        #pragma unroll
        for (int pp = 0; pp < 4; ++pp) {
            int row = pp * 16 + r0;
            int gn  = base + row;
            float4 va = make_float4(0.f, 0.f, 0.f, 0.f);
            float4 vx = make_float4(0.f, 0.f, 0.f, 0.f);
            if (gn < N) {
                va = *(const float4*)&agg[(size_t)gn * D + c4];
                vx = *(const float4*)&in[(size_t)gn * D + c4];
            }
            if (MODE != 0) {
                vx.x = vx.x * aff_a[c4 + 0] + aff_c[c4 + 0];
                vx.y = vx.y * aff_a[c4 + 1] + aff_c[c4 + 1];
                vx.z = vx.z * aff_a[c4 + 2] + aff_c[c4 + 2];
                vx.w = vx.w * aff_a[c4 + 3] + aff_c[c4 + 3];
            }
            *(float4*)&aggs[row * RS + c4] = va;
            *(float4*)&xs[row * RS + c4]   = vx;
        }
    }
    __syncthreads();

    // matmul: wave w computes features [w*16, w*16+16) for all 64 nodes; lane = node
    float acc[16];
    #pragma unroll
    for (int jj = 0; jj < 16; ++jj) acc[jj] = 0.f;
    const int jg = wave * 16;
    const int n  = lane;
    for (int k = 0; k < D; k += 4) {
        float4 a4 = *(const float4*)&aggs[n * RS + k];
        float4 x4 = *(const float4*)&xs[n * RS + k];
        const float* ap = (const float*)&a4;
        const float* xp = (const float*)&x4;
        #pragma unroll
        for (int kk = 0; kk < 4; ++kk) {
            const float avv = ap[kk];
            const float xvv = xp[kk];
            const float* wlr = &WlS[(k + kk) * D + jg];
            const float* wrr = &WrS[(k + kk) * D + jg];
            #pragma unroll
            for (int jj = 0; jj < 16; ++jj) {
                acc[jj] += avv * wlr[jj];
                acc[jj] += xvv * wrr[jj];
            }
        }
    }
    __syncthreads();  // all waves done reading aggs/xs

    if (MODE != 2) {
        float hv[16];
        #pragma unroll
        for (int jj = 0; jj < 16; ++jj) {
            float v = acc[jj] + bl[jg + jj];
            hv[jj] = lrelu(v);
        }
        // transpose through LDS (reuse aggs) for coalesced writeback
        #pragma unroll
        for (int q = 0; q < 4; ++q) {
            float4 v4 = make_float4(hv[q * 4 + 0], hv[q * 4 + 1], hv[q * 4 + 2], hv[q * 4 + 3]);
            *(float4*)&aggs[n * RS + jg + q * 4] = v4;
        }
        __syncthreads();
        {
            const int r0 = tid >> 4;
            const int c4 = (tid & 15) * 4;
            #pragma unroll
            for (int pp = 0; pp < 4; ++pp) {
                int row = pp * 16 + r0;
                int gn  = base + row;
                if (gn < N)
                    *(float4*)&hout[(size_t)gn * D + c4] = *(const float4*)&aggs[row * RS + c4];
            }
        }
        // BN partial stats: sum over nodes (= lanes) per feature
        bool valid = (base + n) < N;
        #pragma unroll
        for (int jj = 0; jj < 16; ++jj) {
            float s1 = valid ? hv[jj] : 0.f;
            float s2 = s1 * s1;
            #pragma unroll
            for (int o = 32; o > 0; o >>= 1) {
                s1 += __shfl_xor(s1, o, 64);
                s2 += __shfl_xor(s2, o, 64);
            }
            if (lane == 0) {
                atomicAdd(&sums[jg + jj], s1);
                atomicAdd(&sumsq[jg + jj], s2);
            }
        }
    } else {
        // fused FC head: out[n] = lrelu(h2) . wfc + bfc
        float s = 0.f;
        #pragma unroll
        for (int jj = 0; jj < 16; ++jj) {
            float v = acc[jj] + bl[jg + jj];
            s += lrelu(v) * wfc[jg + jj];
        }
        aggs[wave * 64 + n] = s;   // scratch reuse, post-barrier
        __syncthreads();
        if (wave == 0) {
            int gn = base + lane;
            if (gn < N)
                out[gn] = aggs[lane] + aggs[64 + lane] + aggs[128 + lane] + aggs[192 + lane] + bfc[0];
        }
    }
}

// ---------------- launch ----------------

extern "C" void kernel_launch(void* const* d_in, const int* in_sizes, int n_in,
                              void* d_out, int out_size, void* d_ws, size_t ws_size,
                              hipStream_t stream) {
    const float* x   = (const float*)d_in[0];
    const int*   ei  = (const int*)d_in[1];
    const float* W0l = (const float*)d_in[2];
    const float* b0  = (const float*)d_in[3];
    const float* W0r = (const float*)d_in[4];
    const float* g0  = (const float*)d_in[5];
    const float* be0 = (const float*)d_in[6];
    const float* W1l = (const float*)d_in[7];
    const float* b1  = (const float*)d_in[8];
    const float* W1r = (const float*)d_in[9];
    const float* g1  = (const float*)d_in[10];
    const float* be1 = (const float*)d_in[11];
    const float* W2l = (const float*)d_in[12];
    const float* b2  = (const float*)d_in[13];
    const float* W2r = (const float*)d_in[14];
    const float* Wfc = (const float*)d_in[15];
    const float* bfc = (const float*)d_in[16];
    float* out = (float*)d_out;

    const int N = in_sizes[0] / D;
    const int E = in_sizes[1] / 2;
    const int* src = ei;
    const int* dst = ei + E;

    char* p = (char*)d_ws;
    auto carve = [&](size_t bytes) {
        char* r = p;
        p += (bytes + 255) & ~(size_t)255;
        return r;
    };
    int*   cnt     = (int*)carve((size_t)2 * N * 4);     // cnt + cursor contiguous
    int*   cursor  = cnt + N;
    int*   offsets = (int*)carve((size_t)(N + 1) * 4);
    int*   psum    = (int*)carve(1024 * 4);
    int*   col     = (int*)carve((size_t)E * 4);
    float* stats   = (float*)carve(256 * 4);             // sums0,sumsq0,sums1,sumsq1
    float* aff     = (float*)carve(256 * 4);             // a0,c0,a1,c1
    float* h0      = (float*)carve((size_t)N * D * 4);
    float* h1      = (float*)carve((size_t)N * D * 4);
    float* aggbuf  = (float*)carve((size_t)N * D * 4);

    hipMemsetAsync(cnt, 0, (size_t)2 * N * 4, stream);
    hipMemsetAsync(stats, 0, 256 * 4, stream);

    const int ebl = (E + 255) / 256;
    const int nbl = (N + 255) / 256;

    count_kernel<<<ebl, 256, 0, stream>>>(dst, E, cnt);
    scan1_kernel<<<nbl, 256, 0, stream>>>(cnt, N, psum);
    scan2_kernel<<<1, 1024, 0, stream>>>(psum, nbl);
    scan3_kernel<<<nbl, 256, 0, stream>>>(cnt, psum, N, E, offsets);
    fill_kernel<<<ebl, 256, 0, stream>>>(src, dst, E, offsets, cursor, col);

    const int abl = (N + 3) / 4;          // 4 nodes (waves) per block
    const int lbl = (N + NPB - 1) / NPB;
    const float invN = 1.f / (float)N;

    // layer 0
    agg_kernel<0><<<abl, 256, 0, stream>>>(x, offsets, col, nullptr, nullptr, aggbuf, N);
    layer_kernel<0><<<lbl, 256, 0, stream>>>(x, aggbuf, nullptr, nullptr,
                                             W0l, b0, W0r, h0, stats + 0, stats + 64,
                                             nullptr, nullptr, nullptr, N);
    affine_kernel<<<1, 64, 0, stream>>>(stats + 0, stats + 64, g0, be0, aff + 0, aff + 64, invN);
    // layer 1
    agg_kernel<1><<<abl, 256, 0, stream>>>(h0, offsets, col, aff + 0, aff + 64, aggbuf, N);
    layer_kernel<1><<<lbl, 256, 0, stream>>>(h0, aggbuf, aff + 0, aff + 64,
                                             W1l, b1, W1r, h1, stats + 128, stats + 192,
                                             nullptr, nullptr, nullptr, N);
    affine_kernel<<<1, 64, 0, stream>>>(stats + 128, stats + 192, g1, be1, aff + 128, aff + 192, invN);
    // layer 2 + FC head
    agg_kernel<1><<<abl, 256, 0, stream>>>(h1, offsets, col, aff + 128, aff + 192, aggbuf, N);
    layer_kernel<2><<<lbl, 256, 0, stream>>>(h1, aggbuf, aff + 128, aff + 192,
                                             W2l, b2, W2r, nullptr, nullptr, nullptr,
                                             Wfc, bfc, out, N);
}

// Round 8
// 723.593 us; speedup vs baseline: 2.5240x; 2.2929x over previous
//
#include <hip/hip_runtime.h>

#define D 64
#define NPB 64      // nodes per block in layer kernel
#define RS 68       // padded LDS row stride (floats)
#define EPSV 1e-5f
#define SLOPE 0.01f

__device__ __forceinline__ float lrelu(float v) { return v > 0.f ? v : SLOPE * v; }

// ---------------- CSR build ----------------

__global__ void count_kernel(const int* __restrict__ dst, int E, int* __restrict__ cnt) {
    int i = blockIdx.x * 256 + threadIdx.x;
    if (i < E) atomicAdd(&cnt[dst[i]], 1);
}

__global__ void scan1_kernel(const int* __restrict__ cnt, int N, int* __restrict__ psum) {
    __shared__ int sd[256];
    int t = threadIdx.x;
    int i = blockIdx.x * 256 + t;
    sd[t] = (i < N) ? cnt[i] : 0;
    __syncthreads();
    for (int o = 128; o > 0; o >>= 1) {
        if (t < o) sd[t] += sd[t + o];
        __syncthreads();
    }
    if (t == 0) psum[blockIdx.x] = sd[0];
}

__global__ void scan2_kernel(int* __restrict__ psum, int nb) {
    __shared__ int sd[1024];
    int t = threadIdx.x;
    int v = (t < nb) ? psum[t] : 0;
    int x = v;
    sd[t] = x;
    __syncthreads();
    for (int o = 1; o < 1024; o <<= 1) {
        int y = (t >= o) ? sd[t - o] : 0;
        __syncthreads();
        x += y;
        sd[t] = x;
        __syncthreads();
    }
    if (t < nb) psum[t] = x - v;  // exclusive
}

__global__ void scan3_kernel(const int* __restrict__ cnt, const int* __restrict__ psum,
                             int N, int E, int* __restrict__ offsets) {
    __shared__ int sd[256];
    int t = threadIdx.x;
    int i = blockIdx.x * 256 + t;
    int v = (i < N) ? cnt[i] : 0;
    int x = v;
    sd[t] = x;
    __syncthreads();
    for (int o = 1; o < 256; o <<= 1) {
        int y = (t >= o) ? sd[t - o] : 0;
        __syncthreads();
        x += y;
        sd[t] = x;
        __syncthreads();
    }
    if (i < N) offsets[i] = psum[blockIdx.x] + x - v;  // exclusive global
    if (i == 0) offsets[N] = E;
}

__global__ void fill_kernel(const int* __restrict__ src, const int* __restrict__ dst, int E,
                            const int* __restrict__ offsets, int* __restrict__ cursor,
                            int* __restrict__ col) {
    int i = blockIdx.x * 256 + threadIdx.x;
    if (i < E) {
        int d = dst[i];
        int p = atomicAdd(&cursor[d], 1);
        col[offsets[d] + p] = src[i];
    }
}

// ---------------- per-block BN partials -> affine (a,c) ----------------
// blkstats layout: [B][128]: floats 0..63 = sum, 64..127 = sumsq

__global__ void reduce_affine_kernel(const float* __restrict__ blkstats, int B,
                                     const float* __restrict__ g, const float* __restrict__ b,
                                     float* __restrict__ a, float* __restrict__ c, float invN) {
    __shared__ float sd1[4][64];
    __shared__ float sd2[4][64];
    const int t   = threadIdx.x;
    const int f   = t & 63;
    const int seg = t >> 6;
    const int per = (B + 3) / 4;
    const int b0  = seg * per;
    const int b1  = min(B, b0 + per);
    float s1 = 0.f, s2 = 0.f;
    for (int i = b0; i < b1; ++i) {
        s1 += blkstats[(size_t)i * 128 + f];
        s2 += blkstats[(size_t)i * 128 + 64 + f];
    }
    sd1[seg][f] = s1;
    sd2[seg][f] = s2;
    __syncthreads();
    if (t < 64) {
        float su = (sd1[0][f] + sd1[1][f]) + (sd1[2][f] + sd1[3][f]);
        float sq = (sd2[0][f] + sd2[1][f]) + (sd2[2][f] + sd2[3][f]);
        float mu  = su * invN;
        float var = sq * invN - mu * mu;
        float aj  = g[f] * rsqrtf(var + EPSV);
        a[f] = aj;
        c[f] = b[f] - mu * aj;
    }
}

// ---------------- gather-mean kernel: one wave per node ----------------
// AFF=0: agg = mean(in[neighbors])            (deg==0 -> 0)
// AFF=1: agg = affine(mean(in[neighbors]))    (deg==0 -> exact 0, matches ref)

template <int AFF>
__global__ __launch_bounds__(256, 8)
void agg_kernel(const float* __restrict__ in,
                const int* __restrict__ offsets,
                const int* __restrict__ col,
                const float* __restrict__ aff_a,
                const float* __restrict__ aff_c,
                float* __restrict__ aggout,
                int N)
{
    const int node = blockIdx.x * 4 + (threadIdx.x >> 6);
    const int lane = threadIdx.x & 63;
    if (node >= N) return;

    const int beg = offsets[node];
    const int end = offsets[node + 1];
    const int deg = end - beg;

    float a0 = 0.f, a1 = 0.f, a2 = 0.f, a3 = 0.f;
    float a4 = 0.f, a5 = 0.f, a6 = 0.f, a7 = 0.f;

    for (int cb = beg; cb < end; cb += 64) {
        const int nn = min(64, end - cb);
        const int cidx = (lane < nn) ? col[cb + lane] : 0;
        int j = 0;
        for (; j + 8 <= nn; j += 8) {
            const int c0 = __shfl(cidx, j + 0);
            const int c1 = __shfl(cidx, j + 1);
            const int c2 = __shfl(cidx, j + 2);
            const int c3 = __shfl(cidx, j + 3);
            const int c4 = __shfl(cidx, j + 4);
            const int c5 = __shfl(cidx, j + 5);
            const int c6 = __shfl(cidx, j + 6);
            const int c7 = __shfl(cidx, j + 7);
            a0 += in[(size_t)c0 * D + lane];
            a1 += in[(size_t)c1 * D + lane];
            a2 += in[(size_t)c2 * D + lane];
            a3 += in[(size_t)c3 * D + lane];
            a4 += in[(size_t)c4 * D + lane];
            a5 += in[(size_t)c5 * D + lane];
            a6 += in[(size_t)c6 * D + lane];
            a7 += in[(size_t)c7 * D + lane];
        }
        for (; j + 4 <= nn; j += 4) {
            const int c0 = __shfl(cidx, j + 0);
            const int c1 = __shfl(cidx, j + 1);
            const int c2 = __shfl(cidx, j + 2);
            const int c3 = __shfl(cidx, j + 3);
            a0 += in[(size_t)c0 * D + lane];
            a1 += in[(size_t)c1 * D + lane];
            a2 += in[(size_t)c2 * D + lane];
            a3 += in[(size_t)c3 * D + lane];
        }
        for (; j < nn; ++j) {
            const int c = __shfl(cidx, j);
            a0 += in[(size_t)c * D + lane];
        }
    }

    float agg = 0.f;
    if (deg > 0) {
        agg = (((a0 + a1) + (a2 + a3)) + ((a4 + a5) + (a6 + a7))) / (float)deg;
        if (AFF) agg = agg * aff_a[lane] + aff_c[lane];
    }
    aggout[(size_t)node * D + lane] = agg;
}

// ---------------- fused dense layer ----------------
// MODE 0: input raw x (no input affine on self term); outputs h_pre + BN block partials
// MODE 1: input h_pre, affine (a,c) folded into self term; outputs h_pre + BN block partials
// MODE 2: input h_pre, affine on self term; fused FC head -> out[N]
// agg input rows already have affine applied (by agg_kernel).

template <int MODE>
__global__ __launch_bounds__(256, 2)
void layer_kernel(const float* __restrict__ in,
                  const float* __restrict__ agg,
                  const float* __restrict__ aff_a,
                  const float* __restrict__ aff_c,
                  const float* __restrict__ Wl,
                  const float* __restrict__ bl,
                  const float* __restrict__ Wr,
                  float* __restrict__ hout,
                  float* __restrict__ blkstats,
                  const float* __restrict__ wfc,
                  const float* __restrict__ bfc,
                  float* __restrict__ out,
                  int N)
{
    __shared__ float WlS[D * D];
    __shared__ float WrS[D * D];
    __shared__ float aggs[NPB * RS];
    __shared__ float xs[NPB * RS];

    const int tid  = threadIdx.x;
    const int base = blockIdx.x * NPB;
    const int wave = tid >> 6;
    const int lane = tid & 63;

    // stage weights (4096 floats each; 256 threads x 4 float4)
    {
        const float4* wl4 = (const float4*)Wl;
        const float4* wr4 = (const float4*)Wr;
        float4* wls4 = (float4*)WlS;
        float4* wrs4 = (float4*)WrS;
        #pragma unroll
        for (int i = 0; i < 4; ++i) {
            wls4[tid + i * 256] = wl4[tid + i * 256];
            wrs4[tid + i * 256] = wr4[tid + i * 256];
        }
    }
    // stage agg rows + self rows (+input affine on self)
    {
        const int r0 = tid >> 4;          // 0..15
        const int c4 = (tid & 15) * 4;    // 0..60
        #pragma unroll
        for (int pp = 0; pp < 4; ++pp) {
            int row = pp * 16 + r0;
            int gn  = base + row;
            float4 va = make_float4(0.f, 0.f, 0.f, 0.f);
            float4 vx = make_float4(0.f, 0.f, 0.f, 0.f);
            if (gn < N) {
                va = *(const float4*)&agg[(size_t)gn * D + c4];
                vx = *(const float4*)&in[(size_t)gn * D + c4];
            }
            if (MODE != 0) {
                vx.x = vx.x * aff_a[c4 + 0] + aff_c[c4 + 0];
                vx.y = vx.y * aff_a[c4 + 1] + aff_c[c4 + 1];
                vx.z = vx.z * aff_a[c4 + 2] + aff_c[c4 + 2];
                vx.w = vx.w * aff_a[c4 + 3] + aff_c[c4 + 3];
            }
            *(float4*)&aggs[row * RS + c4] = va;
            *(float4*)&xs[row * RS + c4]   = vx;
        }
    }
    __syncthreads();

    // matmul: wave w computes features [w*16, w*16+16) for all 64 nodes; lane = node
    float acc[16];
    #pragma unroll
    for (int jj = 0; jj < 16; ++jj) acc[jj] = 0.f;
    const int jg = wave * 16;
    const int n  = lane;
    for (int k = 0; k < D; k += 4) {
        float4 a4 = *(const float4*)&aggs[n * RS + k];
        float4 x4 = *(const float4*)&xs[n * RS + k];
        const float* ap = (const float*)&a4;
        const float* xp = (const float*)&x4;
        #pragma unroll
        for (int kk = 0; kk < 4; ++kk) {
            const float avv = ap[kk];
            const float xvv = xp[kk];
            const float* wlr = &WlS[(k + kk) * D + jg];
            const float* wrr = &WrS[(k + kk) * D + jg];
            #pragma unroll
            for (int jj = 0; jj < 16; ++jj) {
                acc[jj] += avv * wlr[jj];
                acc[jj] += xvv * wrr[jj];
            }
        }
    }
    __syncthreads();  // all waves done reading aggs/xs

    if (MODE != 2) {
        float hv[16];
        #pragma unroll
        for (int jj = 0; jj < 16; ++jj) {
            float v = acc[jj] + bl[jg + jj];
            hv[jj] = lrelu(v);
        }
        // transpose through LDS (reuse aggs) for coalesced writeback
        #pragma unroll
        for (int q = 0; q < 4; ++q) {
            float4 v4 = make_float4(hv[q * 4 + 0], hv[q * 4 + 1], hv[q * 4 + 2], hv[q * 4 + 3]);
            *(float4*)&aggs[n * RS + jg + q * 4] = v4;
        }
        __syncthreads();
        {
            const int r0 = tid >> 4;
            const int c4 = (tid & 15) * 4;
            #pragma unroll
            for (int pp = 0; pp < 4; ++pp) {
                int row = pp * 16 + r0;
                int gn  = base + row;
                if (gn < N)
                    *(float4*)&hout[(size_t)gn * D + c4] = *(const float4*)&aggs[row * RS + c4];
            }
        }
        // BN partial stats: per-wave shuffle reduce over nodes (= lanes), then
        // NON-ATOMIC per-block partial store (two-stage reduction; atomics on 8
        // cache lines from 1563 blocks serialized at ~25ns/RMW -> ~600us, the
        // round-4 bottleneck).
        bool valid = (base + n) < N;
        #pragma unroll
        for (int jj = 0; jj < 16; ++jj) {
            float s1 = valid ? hv[jj] : 0.f;
            float s2 = s1 * s1;
            #pragma unroll
            for (int o = 32; o > 0; o >>= 1) {
                s1 += __shfl_xor(s1, o, 64);
                s2 += __shfl_xor(s2, o, 64);
            }
            if (lane == 0) {
                blkstats[(size_t)blockIdx.x * 128 + jg + jj]      = s1;
                blkstats[(size_t)blockIdx.x * 128 + 64 + jg + jj] = s2;
            }
        }
    } else {
        // fused FC head: out[n] = lrelu(h2) . wfc + bfc
        float s = 0.f;
        #pragma unroll
        for (int jj = 0; jj < 16; ++jj) {
            float v = acc[jj] + bl[jg + jj];
            s += lrelu(v) * wfc[jg + jj];
        }
        aggs[wave * 64 + n] = s;   // scratch reuse, post-barrier
        __syncthreads();
        if (wave == 0) {
            int gn = base + lane;
            if (gn < N)
                out[gn] = aggs[lane] + aggs[64 + lane] + aggs[128 + lane] + aggs[192 + lane] + bfc[0];
        }
    }
}

// ---------------- launch ----------------

extern "C" void kernel_launch(void* const* d_in, const int* in_sizes, int n_in,
                              void* d_out, int out_size, void* d_ws, size_t ws_size,
                              hipStream_t stream) {
    const float* x   = (const float*)d_in[0];
    const int*   ei  = (const int*)d_in[1];
    const float* W0l = (const float*)d_in[2];
    const float* b0  = (const float*)d_in[3];
    const float* W0r = (const float*)d_in[4];
    const float* g0  = (const float*)d_in[5];
    const float* be0 = (const float*)d_in[6];
    const float* W1l = (const float*)d_in[7];
    const float* b1  = (const float*)d_in[8];
    const float* W1r = (const float*)d_in[9];
    const float* g1  = (const float*)d_in[10];
    const float* be1 = (const float*)d_in[11];
    const float* W2l = (const float*)d_in[12];
    const float* b2  = (const float*)d_in[13];
    const float* W2r = (const float*)d_in[14];
    const float* Wfc = (const float*)d_in[15];
    const float* bfc = (const float*)d_in[16];
    float* out = (float*)d_out;

    const int N = in_sizes[0] / D;
    const int E = in_sizes[1] / 2;
    const int* src = ei;
    const int* dst = ei + E;

    const int lbl = (N + NPB - 1) / NPB;

    char* p = (char*)d_ws;
    auto carve = [&](size_t bytes) {
        char* r = p;
        p += (bytes + 255) & ~(size_t)255;
        return r;
    };
    int*   cnt      = (int*)carve((size_t)2 * N * 4);     // cnt + cursor contiguous
    int*   cursor   = cnt + N;
    int*   offsets  = (int*)carve((size_t)(N + 1) * 4);
    int*   psum     = (int*)carve(1024 * 4);
    int*   col      = (int*)carve((size_t)E * 4);
    float* blkstats = (float*)carve((size_t)lbl * 128 * 4);
    float* aff      = (float*)carve(256 * 4);             // a0,c0,a1,c1
    float* h0       = (float*)carve((size_t)N * D * 4);
    float* h1       = (float*)carve((size_t)N * D * 4);
    float* aggbuf   = (float*)carve((size_t)N * D * 4);

    hipMemsetAsync(cnt, 0, (size_t)2 * N * 4, stream);

    const int ebl = (E + 255) / 256;
    const int nbl = (N + 255) / 256;

    count_kernel<<<ebl, 256, 0, stream>>>(dst, E, cnt);
    scan1_kernel<<<nbl, 256, 0, stream>>>(cnt, N, psum);
    scan2_kernel<<<1, 1024, 0, stream>>>(psum, nbl);
    scan3_kernel<<<nbl, 256, 0, stream>>>(cnt, psum, N, E, offsets);
    fill_kernel<<<ebl, 256, 0, stream>>>(src, dst, E, offsets, cursor, col);

    const int abl = (N + 3) / 4;          // 4 nodes (waves) per block
    const float invN = 1.f / (float)N;

    // layer 0
    agg_kernel<0><<<abl, 256, 0, stream>>>(x, offsets, col, nullptr, nullptr, aggbuf, N);
    layer_kernel<0><<<lbl, 256, 0, stream>>>(x, aggbuf, nullptr, nullptr,
                                             W0l, b0, W0r, h0, blkstats,
                                             nullptr, nullptr, nullptr, N);
    reduce_affine_kernel<<<1, 256, 0, stream>>>(blkstats, lbl, g0, be0, aff + 0, aff + 64, invN);
    // layer 1
    agg_kernel<1><<<abl, 256, 0, stream>>>(h0, offsets, col, aff + 0, aff + 64, aggbuf, N);
    layer_kernel<1><<<lbl, 256, 0, stream>>>(h0, aggbuf, aff + 0, aff + 64,
                                             W1l, b1, W1r, h1, blkstats,
                                             nullptr, nullptr, nullptr, N);
    reduce_affine_kernel<<<1, 256, 0, stream>>>(blkstats, lbl, g1, be1, aff + 128, aff + 192, invN);
    // layer 2 + FC head
    agg_kernel<1><<<abl, 256, 0, stream>>>(h1, offsets, col, aff + 128, aff + 192, aggbuf, N);
    layer_kernel<2><<<lbl, 256, 0, stream>>>(h1, aggbuf, aff + 128, aff + 192,
                                             W2l, b2, W2r, nullptr, nullptr,
                                             Wfc, bfc, out, N);
}

// Round 13
// 533.623 us; speedup vs baseline: 3.4226x; 1.3560x over previous
//
#include <hip/hip_runtime.h>

#define D 64
#define NPB 64      // nodes per block in layer kernel
#define RS 68       // padded LDS row stride (floats)
#define EPSV 1e-5f
#define SLOPE 0.01f
#define R1B 64      // blocks in stage-1 stats reduce

__device__ __forceinline__ float lrelu(float v) { return v > 0.f ? v : SLOPE * v; }

// ---------------- CSR build ----------------

__global__ void count_kernel(const int* __restrict__ dst, int E, int* __restrict__ cnt) {
    int i = blockIdx.x * 256 + threadIdx.x;
    if (i < E) atomicAdd(&cnt[dst[i]], 1);
}

__global__ void scan1_kernel(const int* __restrict__ cnt, int N, int* __restrict__ psum) {
    __shared__ int sd[256];
    int t = threadIdx.x;
    int i = blockIdx.x * 256 + t;
    sd[t] = (i < N) ? cnt[i] : 0;
    __syncthreads();
    for (int o = 128; o > 0; o >>= 1) {
        if (t < o) sd[t] += sd[t + o];
        __syncthreads();
    }
    if (t == 0) psum[blockIdx.x] = sd[0];
}

__global__ void scan2_kernel(int* __restrict__ psum, int nb) {
    __shared__ int sd[1024];
    int t = threadIdx.x;
    int v = (t < nb) ? psum[t] : 0;
    int x = v;
    sd[t] = x;
    __syncthreads();
    for (int o = 1; o < 1024; o <<= 1) {
        int y = (t >= o) ? sd[t - o] : 0;
        __syncthreads();
        x += y;
        sd[t] = x;
        __syncthreads();
    }
    if (t < nb) psum[t] = x - v;  // exclusive
}

__global__ void scan3_kernel(const int* __restrict__ cnt, const int* __restrict__ psum,
                             int N, int E, int* __restrict__ offsets) {
    __shared__ int sd[256];
    int t = threadIdx.x;
    int i = blockIdx.x * 256 + t;
    int v = (i < N) ? cnt[i] : 0;
    int x = v;
    sd[t] = x;
    __syncthreads();
    for (int o = 1; o < 256; o <<= 1) {
        int y = (t >= o) ? sd[t - o] : 0;
        __syncthreads();
        x += y;
        sd[t] = x;
        __syncthreads();
    }
    if (i < N) offsets[i] = psum[blockIdx.x] + x - v;  // exclusive global
    if (i == 0) offsets[N] = E;
}

__global__ void fill_kernel(const int* __restrict__ src, const int* __restrict__ dst, int E,
                            const int* __restrict__ offsets, int* __restrict__ cursor,
                            int* __restrict__ col) {
    int i = blockIdx.x * 256 + threadIdx.x;
    if (i < E) {
        int d = dst[i];
        int p = atomicAdd(&cursor[d], 1);
        col[offsets[d] + p] = src[i];
    }
}

// ---------------- BN stats two-stage parallel reduce ----------------
// blkstats layout: [B][128]: floats 0..63 = sum, 64..127 = sumsq
// Stage 1: 64 blocks; block b accumulates rows i where (i mod 512) == b*8+rg,
//          rg = threadIdx/32, float4 column = threadIdx%32. LDS tree over 8
//          rowgroups -> partial[b][128]. (Round-8 single-block reduce was
//          110us latency-bound at 0.04% occupancy.)

__global__ void reduce1_kernel(const float* __restrict__ blkstats, int B,
                               float* __restrict__ partial) {
    __shared__ float4 sd[256];
    const int t    = threadIdx.x;
    const int c4   = t & 31;   // float4 column (32 x 4 = 128 floats)
    const int rg   = t >> 5;   // rowgroup 0..7
    float4 acc = make_float4(0.f, 0.f, 0.f, 0.f);
    for (int i = blockIdx.x * 8 + rg; i < B; i += R1B * 8) {
        float4 v = *(const float4*)&blkstats[(size_t)i * 128 + c4 * 4];
        acc.x += v.x; acc.y += v.y; acc.z += v.z; acc.w += v.w;
    }
    sd[t] = acc;
    __syncthreads();
    #pragma unroll
    for (int o = 4; o > 0; o >>= 1) {
        if (rg < o) {
            float4 a = sd[rg * 32 + c4];
            float4 b = sd[(rg + o) * 32 + c4];
            a.x += b.x; a.y += b.y; a.z += b.z; a.w += b.w;
            sd[rg * 32 + c4] = a;
        }
        __syncthreads();
    }
    if (t < 32)
        *(float4*)&partial[(size_t)blockIdx.x * 128 + c4 * 4] = sd[c4];
}

// Stage 2: one block reduces partial[64][128] and computes affine (a,c).
__global__ void reduce2_affine_kernel(const float* __restrict__ partial,
                                      const float* __restrict__ g, const float* __restrict__ b,
                                      float* __restrict__ a, float* __restrict__ c, float invN) {
    __shared__ float sd[2][128];
    const int t    = threadIdx.x;   // 256
    const int f    = t & 127;
    const int half = t >> 7;
    float s = 0.f;
    for (int i = half; i < R1B; i += 2)
        s += partial[(size_t)i * 128 + f];
    sd[half][f] = s;
    __syncthreads();
    if (t < 64) {
        float su = sd[0][t]      + sd[1][t];
        float sq = sd[0][64 + t] + sd[1][64 + t];
        float mu  = su * invN;
        float var = sq * invN - mu * mu;
        float aj  = g[t] * rsqrtf(var + EPSV);
        a[t] = aj;
        c[t] = b[t] - mu * aj;
    }
}

// ---------------- gather-mean kernel: one wave per node ----------------
// AFF=0: agg = mean(in[neighbors])            (deg==0 -> 0)
// AFF=1: agg = affine(mean(in[neighbors]))    (deg==0 -> exact 0, matches ref)

template <int AFF>
__global__ __launch_bounds__(256, 8)
void agg_kernel(const float* __restrict__ in,
                const int* __restrict__ offsets,
                const int* __restrict__ col,
                const float* __restrict__ aff_a,
                const float* __restrict__ aff_c,
                float* __restrict__ aggout,
                int N)
{
    const int node = blockIdx.x * 4 + (threadIdx.x >> 6);
    const int lane = threadIdx.x & 63;
    if (node >= N) return;

    const int beg = offsets[node];
    const int end = offsets[node + 1];
    const int deg = end - beg;

    float a0 = 0.f, a1 = 0.f, a2 = 0.f, a3 = 0.f;
    float a4 = 0.f, a5 = 0.f, a6 = 0.f, a7 = 0.f;

    for (int cb = beg; cb < end; cb += 64) {
        const int nn = min(64, end - cb);
        const int cidx = (lane < nn) ? col[cb + lane] : 0;
        int j = 0;
        for (; j + 8 <= nn; j += 8) {
            const int c0 = __shfl(cidx, j + 0);
            const int c1 = __shfl(cidx, j + 1);
            const int c2 = __shfl(cidx, j + 2);
            const int c3 = __shfl(cidx, j + 3);
            const int c4 = __shfl(cidx, j + 4);
            const int c5 = __shfl(cidx, j + 5);
            const int c6 = __shfl(cidx, j + 6);
            const int c7 = __shfl(cidx, j + 7);
            a0 += in[(size_t)c0 * D + lane];
            a1 += in[(size_t)c1 * D + lane];
            a2 += in[(size_t)c2 * D + lane];
            a3 += in[(size_t)c3 * D + lane];
            a4 += in[(size_t)c4 * D + lane];
            a5 += in[(size_t)c5 * D + lane];
            a6 += in[(size_t)c6 * D + lane];
            a7 += in[(size_t)c7 * D + lane];
        }
        for (; j + 4 <= nn; j += 4) {
            const int c0 = __shfl(cidx, j + 0);
            const int c1 = __shfl(cidx, j + 1);
            const int c2 = __shfl(cidx, j + 2);
            const int c3 = __shfl(cidx, j + 3);
            a0 += in[(size_t)c0 * D + lane];
            a1 += in[(size_t)c1 * D + lane];
            a2 += in[(size_t)c2 * D + lane];
            a3 += in[(size_t)c3 * D + lane];
        }
        for (; j < nn; ++j) {
            const int c = __shfl(cidx, j);
            a0 += in[(size_t)c * D + lane];
        }
    }

    float agg = 0.f;
    if (deg > 0) {
        agg = (((a0 + a1) + (a2 + a3)) + ((a4 + a5) + (a6 + a7))) / (float)deg;
        if (AFF) agg = agg * aff_a[lane] + aff_c[lane];
    }
    aggout[(size_t)node * D + lane] = agg;
}

// ---------------- fused dense layer ----------------
// MODE 0: input raw x (no input affine on self term); outputs h_pre + BN block partials
// MODE 1: input h_pre, affine (a,c) folded into self term; outputs h_pre + BN block partials
// MODE 2: input h_pre, affine on self term; fused FC head -> out[N]
// agg input rows already have affine applied (by agg_kernel).

template <int MODE>
__global__ __launch_bounds__(256, 2)
void layer_kernel(const float* __restrict__ in,
                  const float* __restrict__ agg,
                  const float* __restrict__ aff_a,
                  const float* __restrict__ aff_c,
                  const float* __restrict__ Wl,
                  const float* __restrict__ bl,
                  const float* __restrict__ Wr,
                  float* __restrict__ hout,
                  float* __restrict__ blkstats,
                  const float* __restrict__ wfc,
                  const float* __restrict__ bfc,
                  float* __restrict__ out,
                  int N)
{
    __shared__ float WlS[D * D];
    __shared__ float WrS[D * D];
    __shared__ float aggs[NPB * RS];
    __shared__ float xs[NPB * RS];

    const int tid  = threadIdx.x;
    const int base = blockIdx.x * NPB;
    const int wave = tid >> 6;
    const int lane = tid & 63;

    // stage weights (4096 floats each; 256 threads x 4 float4)
    {
        const float4* wl4 = (const float4*)Wl;
        const float4* wr4 = (const float4*)Wr;
        float4* wls4 = (float4*)WlS;
        float4* wrs4 = (float4*)WrS;
        #pragma unroll
        for (int i = 0; i < 4; ++i) {
            wls4[tid + i * 256] = wl4[tid + i * 256];
            wrs4[tid + i * 256] = wr4[tid + i * 256];
        }
    }
    // stage agg rows + self rows (+input affine on self)
    {
        const int r0 = tid >> 4;          // 0..15
        const int c4 = (tid & 15) * 4;    // 0..60
        #pragma unroll
        for (int pp = 0; pp < 4; ++pp) {
            int row = pp * 16 + r0;
            int gn  = base + row;
            float4 va = make_float4(0.f, 0.f, 0.f, 0.f);
            float4 vx = make_float4(0.f, 0.f, 0.f, 0.f);
            if (gn < N) {
                va = *(const float4*)&agg[(size_t)gn * D + c4];
                vx = *(const float4*)&in[(size_t)gn * D + c4];
            }
            if (MODE != 0) {
                vx.x = vx.x * aff_a[c4 + 0] + aff_c[c4 + 0];
                vx.y = vx.y * aff_a[c4 + 1] + aff_c[c4 + 1];
                vx.z = vx.z * aff_a[c4 + 2] + aff_c[c4 + 2];
                vx.w = vx.w * aff_a[c4 + 3] + aff_c[c4 + 3];
            }
            *(float4*)&aggs[row * RS + c4] = va;
            *(float4*)&xs[row * RS + c4]   = vx;
        }
    }
    __syncthreads();

    // matmul: wave w computes features [w*16, w*16+16) for all 64 nodes; lane = node
    float acc[16];
    #pragma unroll
    for (int jj = 0; jj < 16; ++jj) acc[jj] = 0.f;
    const int jg = wave * 16;
    const int n  = lane;
    for (int k = 0; k < D; k += 4) {
        float4 a4 = *(const float4*)&aggs[n * RS + k];
        float4 x4 = *(const float4*)&xs[n * RS + k];
        const float* ap = (const float*)&a4;
        const float* xp = (const float*)&x4;
        #pragma unroll
        for (int kk = 0; kk < 4; ++kk) {
            const float avv = ap[kk];
            const float xvv = xp[kk];
            const float* wlr = &WlS[(k + kk) * D + jg];
            const float* wrr = &WrS[(k + kk) * D + jg];
            #pragma unroll
            for (int jj = 0; jj < 16; ++jj) {
                acc[jj] += avv * wlr[jj];
                acc[jj] += xvv * wrr[jj];
            }
        }
    }
    __syncthreads();  // all waves done reading aggs/xs

    if (MODE != 2) {
        float hv[16];
        #pragma unroll
        for (int jj = 0; jj < 16; ++jj) {
            float v = acc[jj] + bl[jg + jj];
            hv[jj] = lrelu(v);
        }
        // transpose through LDS (reuse aggs) for coalesced writeback
        #pragma unroll
        for (int q = 0; q < 4; ++q) {
            float4 v4 = make_float4(hv[q * 4 + 0], hv[q * 4 + 1], hv[q * 4 + 2], hv[q * 4 + 3]);
            *(float4*)&aggs[n * RS + jg + q * 4] = v4;
        }
        __syncthreads();
        {
            const int r0 = tid >> 4;
            const int c4 = (tid & 15) * 4;
            #pragma unroll
            for (int pp = 0; pp < 4; ++pp) {
                int row = pp * 16 + r0;
                int gn  = base + row;
                if (gn < N)
                    *(float4*)&hout[(size_t)gn * D + c4] = *(const float4*)&aggs[row * RS + c4];
            }
        }
        // BN partial stats: per-wave shuffle reduce, non-atomic per-block store
        bool valid = (base + n) < N;
        #pragma unroll
        for (int jj = 0; jj < 16; ++jj) {
            float s1 = valid ? hv[jj] : 0.f;
            float s2 = s1 * s1;
            #pragma unroll
            for (int o = 32; o > 0; o >>= 1) {
                s1 += __shfl_xor(s1, o, 64);
                s2 += __shfl_xor(s2, o, 64);
            }
            if (lane == 0) {
                blkstats[(size_t)blockIdx.x * 128 + jg + jj]      = s1;
                blkstats[(size_t)blockIdx.x * 128 + 64 + jg + jj] = s2;
            }
        }
    } else {
        // fused FC head: out[n] = lrelu(h2) . wfc + bfc
        float s = 0.f;
        #pragma unroll
        for (int jj = 0; jj < 16; ++jj) {
            float v = acc[jj] + bl[jg + jj];
            s += lrelu(v) * wfc[jg + jj];
        }
        aggs[wave * 64 + n] = s;   // scratch reuse, post-barrier
        __syncthreads();
        if (wave == 0) {
            int gn = base + lane;
            if (gn < N)
                out[gn] = aggs[lane] + aggs[64 + lane] + aggs[128 + lane] + aggs[192 + lane] + bfc[0];
        }
    }
}

// ---------------- launch ----------------

extern "C" void kernel_launch(void* const* d_in, const int* in_sizes, int n_in,
                              void* d_out, int out_size, void* d_ws, size_t ws_size,
                              hipStream_t stream) {
    const float* x   = (const float*)d_in[0];
    const int*   ei  = (const int*)d_in[1];
    const float* W0l = (const float*)d_in[2];
    const float* b0  = (const float*)d_in[3];
    const float* W0r = (const float*)d_in[4];
    const float* g0  = (const float*)d_in[5];
    const float* be0 = (const float*)d_in[6];
    const float* W1l = (const float*)d_in[7];
    const float* b1  = (const float*)d_in[8];
    const float* W1r = (const float*)d_in[9];
    const float* g1  = (const float*)d_in[10];
    const float* be1 = (const float*)d_in[11];
    const float* W2l = (const float*)d_in[12];
    const float* b2  = (const float*)d_in[13];
    const float* W2r = (const float*)d_in[14];
    const float* Wfc = (const float*)d_in[15];
    const float* bfc = (const float*)d_in[16];
    float* out = (float*)d_out;

    const int N = in_sizes[0] / D;
    const int E = in_sizes[1] / 2;
    const int* src = ei;
    const int* dst = ei + E;

    const int lbl = (N + NPB - 1) / NPB;

    char* p = (char*)d_ws;
    auto carve = [&](size_t bytes) {
        char* r = p;
        p += (bytes + 255) & ~(size_t)255;
        return r;
    };
    int*   cnt      = (int*)carve((size_t)2 * N * 4);     // cnt + cursor contiguous
    int*   cursor   = cnt + N;
    int*   offsets  = (int*)carve((size_t)(N + 1) * 4);
    int*   psum     = (int*)carve(1024 * 4);
    int*   col      = (int*)carve((size_t)E * 4);
    float* blkstats = (float*)carve((size_t)lbl * 128 * 4);
    float* partial  = (float*)carve((size_t)R1B * 128 * 4);
    float* aff      = (float*)carve(256 * 4);             // a0,c0,a1,c1
    float* h0       = (float*)carve((size_t)N * D * 4);
    float* h1       = (float*)carve((size_t)N * D * 4);
    float* aggbuf   = (float*)carve((size_t)N * D * 4);

    hipMemsetAsync(cnt, 0, (size_t)2 * N * 4, stream);

    const int ebl = (E + 255) / 256;
    const int nbl = (N + 255) / 256;

    count_kernel<<<ebl, 256, 0, stream>>>(dst, E, cnt);
    scan1_kernel<<<nbl, 256, 0, stream>>>(cnt, N, psum);
    scan2_kernel<<<1, 1024, 0, stream>>>(psum, nbl);
    scan3_kernel<<<nbl, 256, 0, stream>>>(cnt, psum, N, E, offsets);
    fill_kernel<<<ebl, 256, 0, stream>>>(src, dst, E, offsets, cursor, col);

    const int abl = (N + 3) / 4;          // 4 nodes (waves) per block
    const float invN = 1.f / (float)N;

    // layer 0
    agg_kernel<0><<<abl, 256, 0, stream>>>(x, offsets, col, nullptr, nullptr, aggbuf, N);
    layer_kernel<0><<<lbl, 256, 0, stream>>>(x, aggbuf, nullptr, nullptr,
                                             W0l, b0, W0r, h0, blkstats,
                                             nullptr, nullptr, nullptr, N);
    reduce1_kernel<<<R1B, 256, 0, stream>>>(blkstats, lbl, partial);
    reduce2_affine_kernel<<<1, 256, 0, stream>>>(partial, g0, be0, aff + 0, aff + 64, invN);
    // layer 1
    agg_kernel<1><<<abl, 256, 0, stream>>>(h0, offsets, col, aff + 0, aff + 64, aggbuf, N);
    layer_kernel<1><<<lbl, 256, 0, stream>>>(h0, aggbuf, aff + 0, aff + 64,
                                             W1l, b1, W1r, h1, blkstats,
                                             nullptr, nullptr, nullptr, N);
    reduce1_kernel<<<R1B, 256, 0, stream>>>(blkstats, lbl, partial);
    reduce2_affine_kernel<<<1, 256, 0, stream>>>(partial, g1, be1, aff + 128, aff + 192, invN);
    // layer 2 + FC head
    agg_kernel<1><<<abl, 256, 0, stream>>>(h1, offsets, col, aff + 128, aff + 192, aggbuf, N);
    layer_kernel<2><<<lbl, 256, 0, stream>>>(h1, aggbuf, aff + 128, aff + 192,
                                             W2l, b2, W2r, nullptr, nullptr,
                                             Wfc, bfc, out, N);
}